// Round 6
// baseline (178.971 us; speedup 1.0000x reference)
//
#include <hip/hip_runtime.h>
#include <cstdint>

typedef unsigned short u16;
typedef __attribute__((ext_vector_type(8))) short bf16x8;
typedef __attribute__((ext_vector_type(4))) float f32x4;

#define B_   128
#define P_   2048
#define NC_  10
#define F_   160      // NC*CLO
#define NBLK 512      // k_pass blocks: 2 per CU
#define PPB  4        // p-tiles per block (all 4 LDS-resident, single-shot)
#define NTHR 512
#define WLS  162      // k_prep wl stride (shorts): k0*81 % 32 = {0,8,16,24} distinct -> 2-way max

__device__ __forceinline__ u16 f2bf(float f) {
    union { float f; unsigned u; } v; v.f = f;
    unsigned r = v.u + 0x7FFFu + ((v.u >> 16) & 1u);   // RNE
    return (u16)(r >> 16);
}
__device__ __forceinline__ float bf2f(u16 h) {
    union { unsigned u; float f; } v; v.u = ((unsigned)h) << 16;
    return v.f;
}

// async global->LDS, 16B per lane; LDS dest = wave-uniform base + lane*16.
__device__ __forceinline__ void gl_lds16(const void* g, void* l) {
    typedef __attribute__((address_space(3))) unsigned lds_uint;
    typedef __attribute__((address_space(1))) const unsigned glob_uint;
    __builtin_amdgcn_global_load_lds((glob_uint*)(uintptr_t)g,
                                     (lds_uint*)(unsigned)(uintptr_t)l, 16, 0, 0);
}

// Fused prep. Blocks 0..4095: squash x along NP=32, bf16, write xb[p] in DMA-deposit
// order with 16B-chunk swizzle (row b: chunk q at b*64B + ((q+(b>>1))&3)*16B).
// Blocks 4096..6143: w[p][k][f] fp32 -> wb[p] bf16 transposed, same swizzle on rows f.
__global__ void k_prep(const float* __restrict__ t, const float* __restrict__ w,
                       u16* __restrict__ xb, u16* __restrict__ wb) {
    const int blk = blockIdx.x, tid = threadIdx.x;
    if (blk < 4096) {
        int g = blk * 256 + tid;
        int pair = g >> 2, sub = g & 3;          // sub = q chunk
        int p = pair & 2047, b = pair >> 11;
        const float4* tg = (const float4*)t;
        int fi = pair * 8 + sub * 2;
        float4 va = tg[fi], vb = tg[fi + 1];
        float ss = va.x*va.x + va.y*va.y + va.z*va.z + va.w*va.w
                 + vb.x*vb.x + vb.y*vb.y + vb.z*vb.z + vb.w*vb.w;
        ss += __shfl_xor(ss, 1);      // quad holds full 32-elem sum
        ss += __shfl_xor(ss, 2);
        float fct = ss / ((1.f + ss) * sqrtf(ss));
        u16 h[8] __attribute__((aligned(16)));
        h[0]=f2bf(va.x*fct); h[1]=f2bf(va.y*fct); h[2]=f2bf(va.z*fct); h[3]=f2bf(va.w*fct);
        h[4]=f2bf(vb.x*fct); h[5]=f2bf(vb.y*fct); h[6]=f2bf(vb.z*fct); h[7]=f2bf(vb.w*fct);
        int off = (sub + (b >> 1)) & 3;
        *(uint4*)(xb + p * 4096 + b * 32 + off * 8) = *(const uint4*)h;
    } else {
        __shared__ u16 wl[32 * WLS];
        int p = blk - 4096;
        const float4* wp = (const float4*)(w + p * 32 * F_);
        for (int e4 = tid; e4 < 1280; e4 += 256) {
            float4 v = wp[e4];
            int k = e4 / 40, fg = e4 % 40;
            u16 h[4] __attribute__((aligned(8)));
            h[0]=f2bf(v.x); h[1]=f2bf(v.y); h[2]=f2bf(v.z); h[3]=f2bf(v.w);
            *(ushort4*)(wl + k * WLS + fg * 4) = *(const ushort4*)h;
        }
        __syncthreads();
        u16* wo = wb + p * 5120;
        for (int sid = tid; sid < 640; sid += 256) {
            int f = sid >> 2, k0 = (sid & 3) << 3, q = sid & 3;
            u16 tmp[8] __attribute__((aligned(16)));
#pragma unroll
            for (int j = 0; j < 8; ++j) tmp[j] = wl[(k0 + j) * WLS + f];
            int off = (q + (f >> 1)) & 3;
            *(uint4*)(wo + f * 32 + off * 8) = *(const uint4*)tmp;
        }
    }
}

// One tile's compute. Tile PP's DMA: waited via fine vmcnt + raw barrier (no drain).
template<int PP, int MODE>
__device__ __forceinline__ void tile_step(
    const u16* __restrict__ xt, const u16* __restrict__ wt,
    f32x4 (&s_acc)[NC_], const float4 (&vv)[NC_],
    int wv, int b, int col, int off8)
{
    // vv loads are issued before the DMAs; in-order vmcnt retirement means
    // "tile PP's deposits landed" == (loads after tile PP) outstanding.
    if (wv < 2) __builtin_amdgcn_s_waitcnt(0x0f70 | (3 * (3 - PP)));
    else        __builtin_amdgcn_s_waitcnt(0x0f70 | (2 * (3 - PP)));
    __builtin_amdgcn_s_barrier();     // raw: no vmcnt(0) drain of tiles PP+1..3

    bf16x8 bfrag = *(const bf16x8*)&xt[b * 32 + off8];   // x[b][k=q*8+j]
    if (MODE == 0) {
#pragma unroll
        for (int n = 0; n < NC_; ++n) {
            bf16x8 afrag = *(const bf16x8*)&wt[(n * 16 + col) * 32 + off8];
            s_acc[n] = __builtin_amdgcn_mfma_f32_16x16x32_bf16(afrag, bfrag, s_acc[n], 0, 0, 0);
        }
    } else {
        float tt[NC_];
#pragma unroll
        for (int n = 0; n < NC_; ++n) {
            bf16x8 afrag = *(const bf16x8*)&wt[(n * 16 + col) * 32 + off8];
            f32x4 z = {0.f, 0.f, 0.f, 0.f};
            f32x4 acc = __builtin_amdgcn_mfma_f32_16x16x32_bf16(afrag, bfrag, z, 0, 0, 0);
            float t = acc[0]*vv[n].x + acc[1]*vv[n].y + acc[2]*vv[n].z + acc[3]*vv[n].w;
            t += __shfl_xor(t, 16);   // full 16-elem dot over k'
            t += __shfl_xor(t, 32);
            tt[n] = t;
        }
        float mx = tt[0];
#pragma unroll
        for (int n = 1; n < NC_; ++n) mx = fmaxf(mx, tt[n]);
        float den = 0.f;
#pragma unroll
        for (int n = 0; n < NC_; ++n) { tt[n] = __expf(tt[n] - mx); den += tt[n]; }
        float inv = 1.f / den;
#pragma unroll
        for (int n = 0; n < NC_; ++n) {   // recompute acc: keeps live regs < 128
            bf16x8 afrag = *(const bf16x8*)&wt[(n * 16 + col) * 32 + off8];
            f32x4 z = {0.f, 0.f, 0.f, 0.f};
            f32x4 acc = __builtin_amdgcn_mfma_f32_16x16x32_bf16(afrag, bfrag, z, 0, 0, 0);
            float cf = tt[n] * inv;
#pragma unroll
            for (int r = 0; r < 4; ++r) s_acc[n][r] += cf * acc[r];
        }
    }
}

// One routing pass. All 4 p-tiles DMA'd up front (single-shot quad buffer),
// fine vmcnt waits, raw barriers. MODE 0: c=0.1 uniform. MODE>=1: t = u.vprev
// (bias folded algebraically), softmax over n, weighted sum. Epilogue stages
// s through LDS for fully coalesced global stores.
template<int MODE>
__global__ __launch_bounds__(NTHR, 2) void k_pass(
        const u16* __restrict__ xb, const u16* __restrict__ wb,
        const float* __restrict__ vprev, u16* __restrict__ s_part)
{
    __shared__ __align__(16) u16 xt[PPB][4096];   // 32768 B
    __shared__ __align__(16) u16 wt[PPB][5120];   // 40960 B (reused as epilogue stage)
    const int tid = threadIdx.x, blk = blockIdx.x;
    const int L = tid & 63, wv = tid >> 6;
    const int q = L >> 4, col = L & 15;
    const int b = wv * 16 + col;
    const int p0 = blk * PPB;
    const int off8 = ((q + (col >> 1)) & 3) * 8;   // swizzled 16B-chunk selector

    float4 vv[NC_];
    if (MODE != 0) {      // issued FIRST: oldest in vmcnt order
#pragma unroll
        for (int n = 0; n < NC_; ++n)
            vv[n] = *(const float4*)(vprev + b * F_ + n * 16 + q * 4);
    }

    // issue all 4 tiles' DMA now; nothing re-issued inside the loop
#pragma unroll
    for (int t = 0; t < PPB; ++t) {
        int p = p0 + t;
        gl_lds16(xb + p * 4096 + wv * 512 + L * 8, &xt[t][wv * 512]);
        gl_lds16(wb + p * 5120 + wv * 512 + L * 8, &wt[t][wv * 512]);
        if (wv < 2)
            gl_lds16(wb + p * 5120 + (8 + wv) * 512 + L * 8, &wt[t][(8 + wv) * 512]);
    }

    f32x4 s_acc[NC_];
#pragma unroll
    for (int n = 0; n < NC_; ++n) s_acc[n] = (f32x4){0.f, 0.f, 0.f, 0.f};

    tile_step<0, MODE>(xt[0], wt[0], s_acc, vv, wv, b, col, off8);
    tile_step<1, MODE>(xt[1], wt[1], s_acc, vv, wv, b, col, off8);
    tile_step<2, MODE>(xt[2], wt[2], s_acc, vv, wv, b, col, off8);
    tile_step<3, MODE>(xt[3], wt[3], s_acc, vv, wv, b, col, off8);

    // epilogue: stage s (bf16) in LDS over the dead wt buffer, then coalesced copy
    __syncthreads();                      // all waves done reading wt tiles
    u16* ls = &wt[0][0];                  // 128*160 shorts = 40960 B exactly
    const float sc = (MODE == 0) ? 0.1f : 1.f;
#pragma unroll
    for (int n = 0; n < NC_; ++n) {
        u16 h[4] __attribute__((aligned(8)));
#pragma unroll
        for (int r = 0; r < 4; ++r) h[r] = f2bf(s_acc[n][r] * sc);
        *(ushort4*)&ls[b * F_ + n * 16 + q * 4] = *(const ushort4*)h;
    }
    __syncthreads();
    const uint4* lsv = (const uint4*)ls;
    uint4* gp = (uint4*)(s_part + blk * (B_ * F_));
#pragma unroll
    for (int i = 0; i < 5; ++i)           // 2560 uint4 = 40960 B, fully coalesced
        gp[i * 512 + tid] = lsv[i * 512 + tid];
}

// Sum bf16 partials over NBLK groups, squash along CLO=16.
// ADD: write squash(s) + vprev (produces v0+v1 for the next pass's logits).
template<int ADD>
__global__ void k_red(const u16* __restrict__ s_part,
                      const float* __restrict__ vprev, float* __restrict__ vout) {
    __shared__ float r0s[256], r1s[256];
    const int tid = threadIdx.x, blk = blockIdx.x;
    const int pid = tid & 31, part = tid >> 5;
    const uint* sp = (const uint*)s_part;
    const int opair = blk * 32 + pid;           // 10240 pairs total
    float a0 = 0.f, a1 = 0.f;
#pragma unroll 8
    for (int g = part; g < NBLK; g += 8) {
        uint u = sp[g * 10240 + opair];
        a0 += bf2f((u16)(u & 0xffff));
        a1 += bf2f((u16)(u >> 16));
    }
    r0s[tid] = a0; r1s[tid] = a1;
    __syncthreads();
    if (tid < 32) {
        float s0 = 0.f, s1 = 0.f;
#pragma unroll
        for (int k = 0; k < 8; ++k) { s0 += r0s[k * 32 + tid]; s1 += r1s[k * 32 + tid]; }
        float sq = s0 * s0 + s1 * s1;
        sq += __shfl_xor(sq, 1);    // 8 lanes = 16 elems of one (b,n)
        sq += __shfl_xor(sq, 2);
        sq += __shfl_xor(sq, 4);
        float fct = sq / ((1.f + sq) * sqrtf(sq));
        float2 o = make_float2(s0 * fct, s1 * fct);
        if (ADD) {
            float2 pv = *(const float2*)(vprev + 2 * (blk * 32 + tid));
            o.x += pv.x; o.y += pv.y;
        }
        *(float2*)(vout + 2 * (blk * 32 + tid)) = o;
    }
}

extern "C" void kernel_launch(void* const* d_in, const int* in_sizes, int n_in,
                              void* d_out, int out_size, void* d_ws, size_t ws_size,
                              hipStream_t stream) {
    const float* tensor = (const float*)d_in[0];
    const float* weight = (const float*)d_in[1];
    float* out = (float*)d_out;
    char* ws = (char*)d_ws;

    u16*   xb     = (u16*)(ws);                       // 16,777,216 B
    u16*   wb     = (u16*)(ws + 16777216);            // 20,971,520 B
    u16*   s_part = (u16*)(ws + 37748736);            // 512*20480*2 = 20,971,520 B
    float* v0     = (float*)(ws + 58720256);          // 81,920 B
    float* vs     = (float*)(ws + 58802176);          // 81,920 B (v0 + v1)

    k_prep<<<6144, 256, 0, stream>>>(tensor, weight, xb, wb);

    k_pass<0><<<NBLK, NTHR, 0, stream>>>(xb, wb, nullptr, s_part);
    k_red<0><<<320, 256, 0, stream>>>(s_part, nullptr, v0);
    k_pass<1><<<NBLK, NTHR, 0, stream>>>(xb, wb, v0, s_part);
    k_red<1><<<320, 256, 0, stream>>>(s_part, v0, vs);
    k_pass<2><<<NBLK, NTHR, 0, stream>>>(xb, wb, vs, s_part);
    k_red<0><<<320, 256, 0, stream>>>(s_part, nullptr, out);
}